// Round 1
// baseline (431.398 us; speedup 1.0000x reference)
//
#include <hip/hip_runtime.h>

typedef __attribute__((ext_vector_type(8))) short short8;
typedef __attribute__((ext_vector_type(4))) float f32x4;

#define LOG2E 1.44269504088896340736f

__device__ __forceinline__ unsigned short f2bf(float f) {
    union { float f; unsigned u; } a; a.f = f;
    unsigned r = a.u + 0x7fffu + ((a.u >> 16) & 1u);   // RNE
    return (unsigned short)(r >> 16);
}
__device__ __forceinline__ unsigned pk2(float x, float y) {
    return (unsigned)f2bf(x) | ((unsigned)f2bf(y) << 16);
}
__device__ __forceinline__ float sigm(float x) {       // sigmoid via exp2+rcp
    return __builtin_amdgcn_rcpf(1.0f + __builtin_amdgcn_exp2f(-LOG2E * x));
}

// B=2048, T=512, I=64, H=32. ONE batch row per wave: 512 blocks x 4 waves.
// LDS ~54.8 KB/block -> 2 blocks/CU -> 2 waves/SIMD so two independent
// recurrence chains interleave (previous version was 1 wave/SIMD, pure
// latency-bound: VALU 37%, MFMA 19%, HBM 9%).
// A-rows 0-15 all carry h(row); lane j owns h column cc=j&31 (lanes 32-63
// are replicas of 0-31 -- divergence-free, writes go to distinct hw slots).
__global__ __launch_bounds__(256, 2) void lstm_fused(
    const float* __restrict__ x,    // [2048,512,64]
    const float* __restrict__ Wih,  // [128,64]
    const float* __restrict__ Whh,  // [128,32]
    const float* __restrict__ bih,  // [128]
    const float* __restrict__ bhh,  // [128]
    const float* __restrict__ Wfc,  // [1,32]
    const float* __restrict__ bfc,  // [1]
    float* __restrict__ out)        // [2048,1]
{
    __shared__ unsigned short Wlds[128 * 80];            // W_ih bf16, stride 80   (20480 B)
    __shared__ float xg_sh[4 * 16 * 132];                // per-wave 1 row xg      (33792 B)
    __shared__ alignas(64) unsigned short hbuf[4 * 64];  // per-wave h bf16        (512 B)

    const int tid  = threadIdx.x;
    const int lane = tid & 63;
    const int wv   = tid >> 6;
    const int b0   = blockIdx.x * 4 + wv;   // one batch row per wave
    const int m    = lane & 15;   // tile col / A-row index
    const int quad = lane >> 4;   // k-quad
    const int cc   = lane & 31;   // owned h column

    // ---- cooperative W_ih -> LDS (bf16, padded rows) ----
    {
        const float4* w4 = (const float4*)Wih;
        unsigned* wl = (unsigned*)Wlds;
        #pragma unroll
        for (int i = 0; i < 8; i++) {
            int fi = tid * 8 + i;            // float4 index, 2048 total
            int g  = fi >> 4;                // gate row
            int k  = (fi & 15) << 2;         // col (float units)
            float4 v = w4[fi];
            wl[g * 40 + (k >> 1) + 0] = pk2(v.x, v.y);
            wl[g * 40 + (k >> 1) + 1] = pk2(v.z, v.w);
        }
    }

    // ---- W_hh B-frags in registers (bf16): tile t, lane holds Whh[16t+m][quad*8..+7] ----
    short8 Bh[8];
    #pragma unroll
    for (int t = 0; t < 8; t++) {
        const float4* wr = (const float4*)(Whh + (size_t)(16 * t + m) * 32 + quad * 8);
        float4 va = wr[0], vb = wr[1];
        union { short8 v; unsigned u[4]; } B;
        B.u[0] = pk2(va.x, va.y); B.u[1] = pk2(va.z, va.w);
        B.u[2] = pk2(vb.x, vb.y); B.u[3] = pk2(vb.z, vb.w);
        Bh[t] = B.v;
    }

    // ---- per-lane scatter bias: biasv[n] = bih[16n+m]+bhh[16n+m] ----
    float biasv[8];
    #pragma unroll
    for (int n = 0; n < 8; n++) biasv[n] = bih[16 * n + m] + bhh[16 * n + m];

    const bool b4 = (lane & 16) != 0;

    __syncthreads();  // Wlds ready; per-wave regions need no further barriers

    const float* xrow = x + ((size_t)b0 * 512 + m) * 64;    // row b0, timestep row m
    float* xgw = xg_sh + wv * 2112;                         // [16 t][132]
    unsigned short* hw = hbuf + wv * 64;

    hw[lane] = 0;               // h=0 (lanes 32-63 write replica slots, never read)
    float c = 0.0f, h = 0.0f;
    const f32x4 z4 = {0.f, 0.f, 0.f, 0.f};

    // prefetch chunk 0
    float4 p0, p1, p2, p3;
    {
        const float4* r0 = (const float4*)xrow;
        p0 = r0[quad * 2];     p1 = r0[quad * 2 + 1];
        p2 = r0[8 + quad * 2]; p3 = r0[8 + quad * 2 + 1];
    }

    for (int ch = 0; ch < 32; ++ch) {
        // ---- pack A-frags (k 0..31, 32..63), bf16 ----
        union { short8 v; unsigned u[4]; } A0, A1;
        A0.u[0] = pk2(p0.x, p0.y); A0.u[1] = pk2(p0.z, p0.w);
        A0.u[2] = pk2(p1.x, p1.y); A0.u[3] = pk2(p1.z, p1.w);
        A1.u[0] = pk2(p2.x, p2.y); A1.u[1] = pk2(p2.z, p2.w);
        A1.u[2] = pk2(p3.x, p3.y); A1.u[3] = pk2(p3.z, p3.w);

        // ---- prefetch next chunk (hidden under the 16-step loop) ----
        {
            const int chn = (ch < 31) ? ch + 1 : 31;
            const float4* n0 = (const float4*)(xrow + (size_t)chn * 1024);
            p0 = n0[quad * 2];     p1 = n0[quad * 2 + 1];
            p2 = n0[8 + quad * 2]; p3 = n0[8 + quad * 2 + 1];
        }

        // ---- xg for this row: 16 MFMAs; scatter [tt][4*cc+gidx] ----
        #pragma unroll
        for (int n = 0; n < 8; n++) {
            const short8 B0 = *(const short8*)&Wlds[(16 * n + m) * 80 + quad * 8];
            const short8 B1 = *(const short8*)&Wlds[(16 * n + m) * 80 + 32 + quad * 8];
            f32x4 ar0 = {0.f, 0.f, 0.f, 0.f};
            ar0 = __builtin_amdgcn_mfma_f32_16x16x32_bf16(A0.v, B0, ar0, 0, 0, 0);
            ar0 = __builtin_amdgcn_mfma_f32_16x16x32_bf16(A1.v, B1, ar0, 0, 0, 0);
            const int pos = ((n & 1) << 6) + 4 * m + (n >> 1);
            #pragma unroll
            for (int r = 0; r < 4; r++) {
                xgw[(quad * 4 + r) * 132 + pos] = ar0[r] + biasv[n];
            }
        }

        // ---- 16 recurrent timesteps ----
        #pragma unroll
        for (int tt = 0; tt < 16; ++tt) {
            // all A rows = h of this wave's row; lane reads its k-chunk quad*8..+7
            const short8 abf = *(const short8*)&hw[quad * 8];
            const f32x4 a0 = __builtin_amdgcn_mfma_f32_16x16x32_bf16(abf, Bh[0], z4, 0, 0, 0);
            const f32x4 a1 = __builtin_amdgcn_mfma_f32_16x16x32_bf16(abf, Bh[1], z4, 0, 0, 0);
            const f32x4 a2 = __builtin_amdgcn_mfma_f32_16x16x32_bf16(abf, Bh[2], z4, 0, 0, 0);
            const f32x4 a3 = __builtin_amdgcn_mfma_f32_16x16x32_bf16(abf, Bh[3], z4, 0, 0, 0);
            const f32x4 a4 = __builtin_amdgcn_mfma_f32_16x16x32_bf16(abf, Bh[4], z4, 0, 0, 0);
            const f32x4 a5 = __builtin_amdgcn_mfma_f32_16x16x32_bf16(abf, Bh[5], z4, 0, 0, 0);
            const f32x4 a6 = __builtin_amdgcn_mfma_f32_16x16x32_bf16(abf, Bh[6], z4, 0, 0, 0);
            const f32x4 a7 = __builtin_amdgcn_mfma_f32_16x16x32_bf16(abf, Bh[7], z4, 0, 0, 0);
            // lane's gates: i=cc (tile b4), f=cc+32, g=cc+64, o=cc+96
            const float hi = b4 ? a1[0] : a0[0];
            const float hf = b4 ? a3[0] : a2[0];
            const float hg = b4 ? a5[0] : a4[0];
            const float ho = b4 ? a7[0] : a6[0];

            const f32x4 xg4 = *(const f32x4*)&xgw[tt * 132 + 4 * cc];
            const float gi = xg4[0] + hi;
            const float gf = xg4[1] + hf;
            const float gg = xg4[2] + hg;
            const float go = xg4[3] + ho;

            const float iv = sigm(gi);
            const float fv = sigm(gf);
            const float gv = fmaf(2.0f, sigm(2.0f * gg), -1.0f);   // tanh
            const float ov = sigm(go);
            c = fmaf(fv, c, iv * gv);
            const float th = fmaf(2.0f, sigm(2.0f * c), -1.0f);    // tanh
            h = ov * th;
            hw[lane] = f2bf(h);      // lanes 0-31 feed the broadcast; 32-63 replica slots
        }
    }

    // ---- fused fc: out[b0] = sum_cc h_cc * Wfc[cc] + bfc ----
    float p = h * Wfc[cc];
    #pragma unroll
    for (int msk = 16; msk >= 1; msk >>= 1) p += __shfl_xor(p, msk);
    if (lane == 0) out[b0] = p + bfc[0];
}

extern "C" void kernel_launch(void* const* d_in, const int* in_sizes, int n_in,
                              void* d_out, int out_size, void* d_ws, size_t ws_size,
                              hipStream_t stream) {
    const float* x   = (const float*)d_in[0];
    const float* Wih = (const float*)d_in[1];
    const float* Whh = (const float*)d_in[2];
    const float* bih = (const float*)d_in[3];
    const float* bhh = (const float*)d_in[4];
    const float* Wfc = (const float*)d_in[5];
    const float* bfc = (const float*)d_in[6];
    float* out = (float*)d_out;
    lstm_fused<<<dim3(512), dim3(256), 0, stream>>>(x, Wih, Whh, bih, bhh, Wfc, bfc, out);
}